// Round 6
// baseline (347.608 us; speedup 1.0000x reference)
//
#include <hip/hip_runtime.h>
#include <hip/hip_bf16.h>

// GCN 2-layer forward, fp32 I/O. dinv folded into stored rows:
//   h1' = dinv * (x @ W1),  agg1 = dinv * (h1'[i] + sum_nbr h1'[s])
//   h2' = dinv * (relu(agg1+b1) @ W2),  out = dinv * (h2'[i] + sum h2'[s]) + b2
//
// Gather layer is XCD-feature-chunked: h tables stored chunk-major
// [NCH][N+1][16 feats]; chunk = blockIdx&(NCH-1) pins each 3.2 MB slab to
// one XCD's L2 (h1: 8 chunks -> 1 XCD each; h2: 4 chunks -> 2 XCDs each).
// Rows are degree-sorted rank slots; self-loop and ZROW padding are
// ordinary CSR entries so pull loops are uniform (no tails/branches).
// (Round 5 = round 4 resubmission: bench failed on GPU acquisition, no data.)
//  * persistent pull blocks (8 chunks x 192 slices) walking ~8 slot-groups
//    each with DOUBLE-BUFFERED LDS index staging: stage group g+1 while
//    computing group g; one barrier per group, no cold prologue per group.
//  * slot metadata packed int4{node,deg,rp} (written by k_bcsr), staged
//    once per block -> no dependent scalar loads per group.
//  * 8 gathers in flight per k-step (2x ds_read_b128 idx + 8 dwordx2),
//    dual accumulator sets for ILP.
// Pipeline:
//  1) k_prep: W1,W2 -> bf16 transposed; bcur init; zero ZROWs
//  2) k_bucket: partition packed {src,dloc} by dst>>9 into ebuf
//  3) k_bcsr:  stage -> hist -> degree counting-sort -> padded scan in
//              rank order -> dinv/meta4 -> self+pad fill -> edge scatter
//  4) h1' = dinv*(x @ W1) -> bf16 chunk-major     (k_gemm1, MFMA)
//  5) aggb = dinv*(gather-sum h1') chunk-major    (k_pull128)
//  6) h2' = dinv*(relu(aggb+b1) @ W2) chunk-major (k_gemm2, MFMA)
//  7) out = dinv*(gather-sum h2') + b2            (k_pull64)

typedef short short8v __attribute__((ext_vector_type(8)));   // 8 bf16 (4 VGPRs)
typedef float f32x4   __attribute__((ext_vector_type(4)));   // MFMA acc / f32 stores
typedef int   int4v   __attribute__((ext_vector_type(4)));   // dwordx4
typedef unsigned uint2v __attribute__((ext_vector_type(2))); // dwordx2

#define BSHIFT 9           // bucket = dst >> 9 (span 512 nodes)
#define BSIZE  512
#define CAPSH  14          // per-bucket capacity 16384 (padded mean ~10K, >40 sigma)
#define CAP    (1 << CAPSH)
#define IDXC2  2048        // staged-index ints per double-buffer half (8 KB)
#define MAXG128 9          // max slot-groups per pull128 block
#define MAXG64  5          // max slot-groups per pull64 block

// RNE fp32 -> bf16 (finite inputs)
__device__ __forceinline__ short f2bf(float f) {
    unsigned u = __float_as_uint(f);
    return (short)((u + 0x7fffu + ((u >> 16) & 1u)) >> 16);
}
__device__ __forceinline__ unsigned pack2bf(float a, float b) {
    return (unsigned)(unsigned short)f2bf(a) | ((unsigned)(unsigned short)f2bf(b) << 16);
}
__device__ __forceinline__ float bflo(unsigned u) { return __uint_as_float(u << 16); }
__device__ __forceinline__ float bfhi(unsigned u) { return __uint_as_float(u & 0xffff0000u); }

// ---- W prep + bucket-cursor init + ZROW zeroing (one launch) ----
__global__ void k_prep(const float* __restrict__ W1, const float* __restrict__ W2,
                       short* __restrict__ w1t, short* __restrict__ w2t,
                       int* __restrict__ bcur, int nbuck,
                       short* __restrict__ bufH, short* __restrict__ bufH2, int N) {
    int b = blockIdx.x;
    int t = threadIdx.x;
    if (b == gridDim.x - 1) {                 // last block: cursors + ZROWs
        if (t < nbuck) bcur[t] = t << CAPSH;
        size_t np1 = (size_t)N + 1;
        if (t < 128) {                        // h1: 8 chunks x 16 feats
            bufH[((size_t)(t >> 4) * np1 + N) * 16 + (t & 15)] = 0;
        } else if (t < 192) {                 // h2: 4 chunks x 16 feats
            int z = t - 128;
            bufH2[((size_t)(z >> 4) * np1 + N) * 16 + (z & 15)] = 0;
        }
        return;
    }
    int i = b * 256 + t;                      // 96 blocks cover 24576 elems
    if (i < 128 * 128) {
        int n = i >> 7, k = i & 127;
        w1t[i] = f2bf(W1[k * 128 + n]);
    } else {
        int j = i - 128 * 128;
        int n = j >> 7, k = j & 127;
        w2t[j] = f2bf(W2[k * 64 + n]);
    }
}

// ---- partition edges into packed ebuf: entry = (src<<9) | (dst&511) ----
__global__ __launch_bounds__(256) void k_bucket(const int* __restrict__ src,
                                                const int* __restrict__ dst,
                                                int* __restrict__ bcur,
                                                unsigned* __restrict__ ebuf,
                                                int E, int nbuck) {
    __shared__ int sdst[4096];
    __shared__ int ssrc[4096];
    __shared__ int hist[256];
    __shared__ int base[256];
    int t = threadIdx.x;
    int e0 = blockIdx.x * 4096;
    for (int i = t; i < nbuck; i += 256) hist[i] = 0;
    for (int i = 0; i < 16; ++i) {                  // single global read
        int k = i * 256 + t;
        int e = e0 + k;
        sdst[k] = (e < E) ? dst[e] : -1;
        ssrc[k] = (e < E) ? src[e] : 0;
    }
    __syncthreads();
    for (int i = 0; i < 16; ++i) {                  // pass 1: LDS histogram
        int d = sdst[i * 256 + t];
        if (d >= 0) atomicAdd(&hist[d >> BSHIFT], 1);
    }
    __syncthreads();
    for (int b = t; b < nbuck; b += 256) {          // pass 2: reserve chunks
        int c = hist[b];
        base[b] = c ? atomicAdd(&bcur[b], c) : 0;
        hist[b] = 0;
    }
    __syncthreads();
    for (int i = 0; i < 16; ++i) {                  // pass 3: grouped writes
        int k = i * 256 + t;
        int d = sdst[k];
        if (d >= 0) {
            int bk = d >> BSHIFT;
            int off = atomicAdd(&hist[bk], 1);
            ebuf[base[bk] + off] = ((unsigned)ssrc[k] << BSHIFT) | (unsigned)(d & (BSIZE - 1));
        }
    }
}

// ---- per-bucket: stage -> hist -> degree counting-sort -> padded scan in
//      rank order -> dinv/meta4 -> self+pad fill -> edge scatter ----
__global__ __launch_bounds__(BSIZE) void k_bcsr(const unsigned* __restrict__ ebuf,
                                                const int* __restrict__ bcur,
                                                float* __restrict__ dinv,
                                                int4v* __restrict__ meta4,
                                                unsigned* __restrict__ csr4, int n) {
    __shared__ unsigned edges[CAP];    // 64 KB
    __shared__ int hist[BSIZE];
    __shared__ int s[BSIZE];
    __shared__ int cur[BSIZE];
    int b = blockIdx.x;
    int t = threadIdx.x;
    hist[t] = 0;
    __syncthreads();
    int base = b << CAPSH;
    int cnt  = bcur[b] - base;
    int lo = b << BSHIFT;
    for (int k = t; k < cnt; k += BSIZE) {          // stage + LDS hist
        unsigned e = ebuf[base + k];
        edges[k] = e;
        atomicAdd(&hist[e & (BSIZE - 1)], 1);
    }
    __syncthreads();
    int v = hist[t];                                // in-degree of local node t
    int node = lo + t;
    bool valid = node < n;
    __syncthreads();                                // all hist reads done
    hist[t] = 0;                                    // reuse as degree histogram
    __syncthreads();
    int key = valid ? min(v, BSIZE - 1) : 0;
    atomicAdd(&hist[key], 1);
    __syncthreads();
    s[t] = hist[t];
    __syncthreads();
    for (int off = 1; off < BSIZE; off <<= 1) {     // inclusive scan of deg-hist
        int add = (t >= off) ? s[t - off] : 0;
        __syncthreads();
        s[t] += add;
        __syncthreads();
    }
    cur[t] = 0;                                     // reuse as per-degree cursor
    __syncthreads();
    int r = (s[key] - hist[key]) + atomicAdd(&cur[key], 1);   // rank (permutation)
    __syncthreads();                                // s reads done before reuse
    int pv = valid ? ((v + 4) & ~3) : 0;            // self + pad, 16B granules
    s[r] = pv;
    __syncthreads();
    for (int off = 1; off < BSIZE; off <<= 1) {     // inclusive scan in rank order
        int add = (t >= off) ? s[t - off] : 0;
        __syncthreads();
        s[t] += add;
        __syncthreads();
    }
    int rp = base + s[r] - pv;                      // row start (16B aligned)
    cur[t] = rp + 1;                                // edges go after the self slot
    int slot = (b << BSHIFT) + r;
    int4v m;
    m.x = valid ? node : -1;
    m.y = valid ? v : 0;
    m.z = rp;
    m.w = 0;
    meta4[slot] = m;
    if (valid) {
        dinv[node] = rsqrtf((float)(v + 1));
        csr4[rp] = (unsigned)node;                  // self entry
        for (int j = v + 1; j < pv; ++j) csr4[rp + j] = (unsigned)n;  // ZROW pads
    }
    __syncthreads();
    for (int k = t; k < cnt; k += BSIZE) {          // scatter src -> csr4
        unsigned e = edges[k];
        int pos = atomicAdd(&cur[e & (BSIZE - 1)], 1);
        csr4[pos] = e >> BSHIFT;
    }
}

// ---- MFMA GEMM1: h1'[64rows,128] = dinv*(bf16(x) @ bf16(W1)) ----
// Output CHUNK-MAJOR: h[chunk][(N+1) rows][16 feats], chunk = feat>>4.
#define LDP 136
__global__ __launch_bounds__(256) void k_gemm1(const float* __restrict__ x,
                                               const short* __restrict__ w1t,
                                               const float* __restrict__ dinv,
                                               short* __restrict__ h, int nrows) {
    __shared__ short xs[64 * LDP];
    __shared__ short wt[128 * LDP];
    int t = threadIdx.x;
    int row0 = blockIdx.x * 64;
    for (int i = 0; i < 16; ++i) {
        int idx = t + i * 256;
        int r = idx >> 5, c4 = idx & 31;
        float4 v = make_float4(0.f, 0.f, 0.f, 0.f);
        if (row0 + r < nrows) v = ((const float4*)x)[(size_t)(row0 + r) * 32 + c4];
        short4 o = make_short4(f2bf(v.x), f2bf(v.y), f2bf(v.z), f2bf(v.w));
        *(short4*)&xs[r * LDP + c4 * 4] = o;
    }
    for (int i = 0; i < 16; ++i) {
        int idx = t + i * 256;
        int n = idx >> 5, c4 = idx & 31;
        *(short4*)&wt[n * LDP + c4 * 4] = ((const short4*)w1t)[idx];
    }
    __syncthreads();
    int wave = t >> 6, lane = t & 63;
    int quad = lane >> 4, c = lane & 15;
    int m0 = wave * 16;
    f32x4 acc[8] = {};
    #pragma unroll
    for (int kc = 0; kc < 4; ++kc) {
        short8v a = *(const short8v*)&xs[(m0 + c) * LDP + kc * 32 + quad * 8];
        #pragma unroll
        for (int nt = 0; nt < 8; ++nt) {
            short8v b = *(const short8v*)&wt[(nt * 16 + c) * LDP + kc * 32 + quad * 8];
            acc[nt] = __builtin_amdgcn_mfma_f32_16x16x32_bf16(a, b, acc[nt], 0, 0, 0);
        }
    }
    size_t slab = ((size_t)nrows + 1) * 16;         // shorts per chunk slab
    #pragma unroll
    for (int r = 0; r < 4; ++r) {
        int row = row0 + m0 + quad * 4 + r;
        if (row < nrows) {
            float dr = dinv[row];                   // fold norm into stored row
            #pragma unroll
            for (int nt = 0; nt < 8; ++nt)
                h[(size_t)nt * slab + (size_t)row * 16 + c] = f2bf(acc[nt][r] * dr);
        }
    }
}

// ---- MFMA GEMM2: h2'[64rows,64] = dinv*(bf16(relu(aggb+b1)) @ bf16(W2)) ----
// aggb CHUNK-MAJOR bf16x2 [8][(N+1)][8]; h2 output CHUNK-MAJOR [4][(N+1)][16].
__global__ __launch_bounds__(256) void k_gemm2(const unsigned* __restrict__ aggb,
                                               const float* __restrict__ b1,
                                               const short* __restrict__ w2t,
                                               const float* __restrict__ dinv,
                                               short* __restrict__ h2, int nrows) {
    __shared__ short xs[64 * LDP];
    __shared__ short wt[64 * LDP];
    int t = threadIdx.x;
    int row0 = blockIdx.x * 64;
    size_t slab8 = ((size_t)nrows + 1) * 8;           // uints per h1-chunk slab
    for (int i = 0; i < 16; ++i) {                    // 64 rows x 64 bf16-pairs
        int idx = t + i * 256;
        int r = idx >> 6, cp = idx & 63;
        unsigned o = 0;
        if (row0 + r < nrows) {
            unsigned u = aggb[(size_t)(cp >> 3) * slab8 + (size_t)(row0 + r) * 8 + (cp & 7)];
            float2 bb = ((const float2*)b1)[cp];
            float vx = fmaxf(bflo(u) + bb.x, 0.f);
            float vy = fmaxf(bfhi(u) + bb.y, 0.f);
            o = pack2bf(vx, vy);
        }
        *(unsigned*)&xs[r * LDP + cp * 2] = o;
    }
    for (int i = 0; i < 8; ++i) {
        int idx = t + i * 256;
        int n = idx >> 5, c4 = idx & 31;
        *(short4*)&wt[n * LDP + c4 * 4] = ((const short4*)w2t)[idx];
    }
    __syncthreads();
    int wave = t >> 6, lane = t & 63;
    int quad = lane >> 4, c = lane & 15;
    int m0 = wave * 16;
    f32x4 acc[4] = {};
    #pragma unroll
    for (int kc = 0; kc < 4; ++kc) {
        short8v av = *(const short8v*)&xs[(m0 + c) * LDP + kc * 32 + quad * 8];
        #pragma unroll
        for (int nt = 0; nt < 4; ++nt) {
            short8v b = *(const short8v*)&wt[(nt * 16 + c) * LDP + kc * 32 + quad * 8];
            acc[nt] = __builtin_amdgcn_mfma_f32_16x16x32_bf16(av, b, acc[nt], 0, 0, 0);
        }
    }
    size_t slab16 = ((size_t)nrows + 1) * 16;         // shorts per h2-chunk slab
    #pragma unroll
    for (int r = 0; r < 4; ++r) {
        int row = row0 + m0 + quad * 4 + r;
        if (row < nrows) {
            float dr = dinv[row];
            #pragma unroll
            for (int nt = 0; nt < 4; ++nt)
                h2[(size_t)nt * slab16 + (size_t)row * 16 + c] = f2bf(acc[nt][r] * dr);
        }
    }
}

// pull 128 feats: persistent blocks, double-buffered idx staging.
// Block = chunk (blockIdx&7) x slice (blockIdx>>3); walks slot-groups
// sg = slice, slice+nbsl, ... Each group = 64 slots, 4-lane node groups.
__global__ __launch_bounds__(256) void k_pull128(const unsigned* __restrict__ h,   // [8][(n+1)][8] bf16x2
                                                 const int4v* __restrict__ meta4,
                                                 const unsigned* __restrict__ csr4,
                                                 unsigned* __restrict__ aggb,      // [8][(n+1)][8]
                                                 int n, int ngroups) {
    __shared__ int sIdx[2][IDXC2];
    __shared__ int4v sMeta[MAXG128 * 64];
    int chunk = blockIdx.x & 7;
    int nbsl  = gridDim.x >> 3;
    int bsl   = blockIdx.x >> 3;
    int t = threadIdx.x;
    if (bsl >= ngroups) return;
    int gcount = (ngroups - bsl + nbsl - 1) / nbsl;   // block-uniform, <= MAXG128
    for (int u = t; u < gcount * 64; u += 256) {      // stage all slot metadata
        int gi = u >> 6, li = u & 63;
        int sg = bsl + gi * nbsl;
        sMeta[u] = __builtin_nontemporal_load(&meta4[(size_t)sg * 64 + li]);
    }
    __syncthreads();

    const unsigned* hc = h + (size_t)chunk * (((size_t)n + 1) * 8);
    unsigned* ab = aggb + (size_t)chunk * (((size_t)n + 1) * 8);
    int lane = t & 63, wv = t >> 6;
    int grp = lane >> 2, sub = lane & 3;
    int li = wv * 16 + grp;

    // stage group 0 into buffer 0
    {
        int4v m0 = sMeta[0], mL = sMeta[63];
        int rpBeg = m0.z;
        int pvL = (mL.x >= 0) ? ((mL.y + 4) & ~3) : 0;
        int range = mL.z + pvL - rpBeg;
        if (range <= IDXC2)
            for (int j = t * 4; j < range; j += 1024)
                *(int4v*)&sIdx[0][j] = __builtin_nontemporal_load((const int4v*)(csr4 + rpBeg + j));
    }
    int cur = 0;
    for (int gi = 0; gi < gcount; ++gi) {
        __syncthreads();                              // sIdx[cur] staged; sIdx[cur^1] free
        if (gi + 1 < gcount) {                        // issue next group's staging
            int4v m0 = sMeta[(gi + 1) * 64], mL = sMeta[(gi + 1) * 64 + 63];
            int rpBeg = m0.z;
            int pvL = (mL.x >= 0) ? ((mL.y + 4) & ~3) : 0;
            int range = mL.z + pvL - rpBeg;
            if (range <= IDXC2)
                for (int j = t * 4; j < range; j += 1024)
                    *(int4v*)&sIdx[cur ^ 1][j] = __builtin_nontemporal_load((const int4v*)(csr4 + rpBeg + j));
        }
        // compute group gi (overlaps the staging loads above)
        int4v m  = sMeta[gi * 64 + li];
        int4v m0 = sMeta[gi * 64], mL = sMeta[gi * 64 + 63];
        int rpBeg = m0.z;
        int pvL = (mL.x >= 0) ? ((mL.y + 4) & ~3) : 0;
        bool fast = (mL.z + pvL - rpBeg) <= IDXC2;
        int node = m.x, v = m.y;
        int pv = (node >= 0) ? ((v + 4) & ~3) : 0;
        float a0 = 0.f, a1 = 0.f, a2 = 0.f, a3 = 0.f;
        float c0 = 0.f, c1 = 0.f, c2 = 0.f, c3 = 0.f;
        if (fast) {
            const int* ip = &sIdx[cur][m.z - rpBeg];
            int k = 0;
            for (; k + 8 <= pv; k += 8) {
                int4v q0 = *(const int4v*)(ip + k);
                int4v q1 = *(const int4v*)(ip + k + 4);
                uint2v g0 = *(const uint2v*)&hc[(q0.x << 3) + (sub << 1)];
                uint2v g1 = *(const uint2v*)&hc[(q0.y << 3) + (sub << 1)];
                uint2v g2 = *(const uint2v*)&hc[(q0.z << 3) + (sub << 1)];
                uint2v g3 = *(const uint2v*)&hc[(q0.w << 3) + (sub << 1)];
                uint2v g4 = *(const uint2v*)&hc[(q1.x << 3) + (sub << 1)];
                uint2v g5 = *(const uint2v*)&hc[(q1.y << 3) + (sub << 1)];
                uint2v g6 = *(const uint2v*)&hc[(q1.z << 3) + (sub << 1)];
                uint2v g7 = *(const uint2v*)&hc[(q1.w << 3) + (sub << 1)];
                a0 += bflo(g0[0]); a1 += bfhi(g0[0]); a2 += bflo(g0[1]); a3 += bfhi(g0[1]);
                a0 += bflo(g1[0]); a1 += bfhi(g1[0]); a2 += bflo(g1[1]); a3 += bfhi(g1[1]);
                a0 += bflo(g2[0]); a1 += bfhi(g2[0]); a2 += bflo(g2[1]); a3 += bfhi(g2[1]);
                a0 += bflo(g3[0]); a1 += bfhi(g3[0]); a2 += bflo(g3[1]); a3 += bfhi(g3[1]);
                c0 += bflo(g4[0]); c1 += bfhi(g4[0]); c2 += bflo(g4[1]); c3 += bfhi(g4[1]);
                c0 += bflo(g5[0]); c1 += bfhi(g5[0]); c2 += bflo(g5[1]); c3 += bfhi(g5[1]);
                c0 += bflo(g6[0]); c1 += bfhi(g6[0]); c2 += bflo(g6[1]); c3 += bfhi(g6[1]);
                c0 += bflo(g7[0]); c1 += bfhi(g7[0]); c2 += bflo(g7[1]); c3 += bfhi(g7[1]);
            }
            if (k < pv) {
                int4v q = *(const int4v*)(ip + k);
                uint2v g0 = *(const uint2v*)&hc[(q.x << 3) + (sub << 1)];
                uint2v g1 = *(const uint2v*)&hc[(q.y << 3) + (sub << 1)];
                uint2v g2 = *(const uint2v*)&hc[(q.z << 3) + (sub << 1)];
                uint2v g3 = *(const uint2v*)&hc[(q.w << 3) + (sub << 1)];
                a0 += bflo(g0[0]); a1 += bfhi(g0[0]); a2 += bflo(g0[1]); a3 += bfhi(g0[1]);
                a0 += bflo(g1[0]); a1 += bfhi(g1[0]); a2 += bflo(g1[1]); a3 += bfhi(g1[1]);
                a0 += bflo(g2[0]); a1 += bfhi(g2[0]); a2 += bflo(g2[1]); a3 += bfhi(g2[1]);
                a0 += bflo(g3[0]); a1 += bfhi(g3[0]); a2 += bflo(g3[1]); a3 += bfhi(g3[1]);
            }
        } else {                                      // rare: big group, global idx
            const unsigned* gp = csr4 + m.z;
            for (int k = 0; k < pv; k += 4) {
                int4v q = *(const int4v*)(gp + k);
                uint2v g0 = *(const uint2v*)&hc[(q.x << 3) + (sub << 1)];
                uint2v g1 = *(const uint2v*)&hc[(q.y << 3) + (sub << 1)];
                uint2v g2 = *(const uint2v*)&hc[(q.z << 3) + (sub << 1)];
                uint2v g3 = *(const uint2v*)&hc[(q.w << 3) + (sub << 1)];
                a0 += bflo(g0[0]); a1 += bfhi(g0[0]); a2 += bflo(g0[1]); a3 += bfhi(g0[1]);
                a0 += bflo(g1[0]); a1 += bfhi(g1[0]); a2 += bflo(g1[1]); a3 += bfhi(g1[1]);
                a0 += bflo(g2[0]); a1 += bfhi(g2[0]); a2 += bflo(g2[1]); a3 += bfhi(g2[1]);
                a0 += bflo(g3[0]); a1 += bfhi(g3[0]); a2 += bflo(g3[1]); a3 += bfhi(g3[1]);
            }
        }
        if (node >= 0) {
            float di = rsqrtf((float)(v + 1));        // == bcsr's dinv bit-identically
            a0 += c0; a1 += c1; a2 += c2; a3 += c3;
            uint2v o2;
            o2[0] = pack2bf(a0 * di, a1 * di);
            o2[1] = pack2bf(a2 * di, a3 * di);
            __builtin_nontemporal_store(o2, (uint2v*)&ab[((size_t)node << 3) + (sub << 1)]);
        }
        cur ^= 1;
    }
}

// pull 64 feats: same persistent/double-buffered structure, 4 chunks
// (chunk = blockIdx&3 -> XCDs {c, c+4}); out = dinv*sum + b2 (fp32).
__global__ __launch_bounds__(256) void k_pull64(const unsigned* __restrict__ h2,   // [4][(n+1)][8] bf16x2
                                                const int4v* __restrict__ meta4,
                                                const unsigned* __restrict__ csr4,
                                                const float* __restrict__ b2,
                                                float* __restrict__ out, int n, int ngroups) {
    __shared__ int sIdx[2][IDXC2];
    __shared__ int4v sMeta[MAXG64 * 64];
    int chunk = blockIdx.x & 3;
    int nbsl  = gridDim.x >> 2;
    int bsl   = blockIdx.x >> 2;
    int t = threadIdx.x;
    if (bsl >= ngroups) return;
    int gcount = (ngroups - bsl + nbsl - 1) / nbsl;   // <= MAXG64
    for (int u = t; u < gcount * 64; u += 256) {
        int gi = u >> 6, li = u & 63;
        int sg = bsl + gi * nbsl;
        sMeta[u] = __builtin_nontemporal_load(&meta4[(size_t)sg * 64 + li]);
    }
    __syncthreads();

    const unsigned* hc = h2 + (size_t)chunk * (((size_t)n + 1) * 8);
    int lane = t & 63, wv = t >> 6;
    int grp = lane >> 2, sub = lane & 3;
    int li = wv * 16 + grp;
    f32x4 bb = *(const f32x4*)&b2[chunk * 16 + sub * 4];

    {
        int4v m0 = sMeta[0], mL = sMeta[63];
        int rpBeg = m0.z;
        int pvL = (mL.x >= 0) ? ((mL.y + 4) & ~3) : 0;
        int range = mL.z + pvL - rpBeg;
        if (range <= IDXC2)
            for (int j = t * 4; j < range; j += 1024)
                *(int4v*)&sIdx[0][j] = __builtin_nontemporal_load((const int4v*)(csr4 + rpBeg + j));
    }
    int cur = 0;
    for (int gi = 0; gi < gcount; ++gi) {
        __syncthreads();
        if (gi + 1 < gcount) {
            int4v m0 = sMeta[(gi + 1) * 64], mL = sMeta[(gi + 1) * 64 + 63];
            int rpBeg = m0.z;
            int pvL = (mL.x >= 0) ? ((mL.y + 4) & ~3) : 0;
            int range = mL.z + pvL - rpBeg;
            if (range <= IDXC2)
                for (int j = t * 4; j < range; j += 1024)
                    *(int4v*)&sIdx[cur ^ 1][j] = __builtin_nontemporal_load((const int4v*)(csr4 + rpBeg + j));
        }
        int4v m  = sMeta[gi * 64 + li];
        int4v m0 = sMeta[gi * 64], mL = sMeta[gi * 64 + 63];
        int rpBeg = m0.z;
        int pvL = (mL.x >= 0) ? ((mL.y + 4) & ~3) : 0;
        bool fast = (mL.z + pvL - rpBeg) <= IDXC2;
        int node = m.x, v = m.y;
        int pv = (node >= 0) ? ((v + 4) & ~3) : 0;
        float a0 = 0.f, a1 = 0.f, a2 = 0.f, a3 = 0.f;
        float c0 = 0.f, c1 = 0.f, c2 = 0.f, c3 = 0.f;
        if (fast) {
            const int* ip = &sIdx[cur][m.z - rpBeg];
            int k = 0;
            for (; k + 8 <= pv; k += 8) {
                int4v q0 = *(const int4v*)(ip + k);
                int4v q1 = *(const int4v*)(ip + k + 4);
                uint2v g0 = *(const uint2v*)&hc[(q0.x << 3) + (sub << 1)];
                uint2v g1 = *(const uint2v*)&hc[(q0.y << 3) + (sub << 1)];
                uint2v g2 = *(const uint2v*)&hc[(q0.z << 3) + (sub << 1)];
                uint2v g3 = *(const uint2v*)&hc[(q0.w << 3) + (sub << 1)];
                uint2v g4 = *(const uint2v*)&hc[(q1.x << 3) + (sub << 1)];
                uint2v g5 = *(const uint2v*)&hc[(q1.y << 3) + (sub << 1)];
                uint2v g6 = *(const uint2v*)&hc[(q1.z << 3) + (sub << 1)];
                uint2v g7 = *(const uint2v*)&hc[(q1.w << 3) + (sub << 1)];
                a0 += bflo(g0[0]); a1 += bfhi(g0[0]); a2 += bflo(g0[1]); a3 += bfhi(g0[1]);
                a0 += bflo(g1[0]); a1 += bfhi(g1[0]); a2 += bflo(g1[1]); a3 += bfhi(g1[1]);
                a0 += bflo(g2[0]); a1 += bfhi(g2[0]); a2 += bflo(g2[1]); a3 += bfhi(g2[1]);
                a0 += bflo(g3[0]); a1 += bfhi(g3[0]); a2 += bflo(g3[1]); a3 += bfhi(g3[1]);
                c0 += bflo(g4[0]); c1 += bfhi(g4[0]); c2 += bflo(g4[1]); c3 += bfhi(g4[1]);
                c0 += bflo(g5[0]); c1 += bfhi(g5[0]); c2 += bflo(g5[1]); c3 += bfhi(g5[1]);
                c0 += bflo(g6[0]); c1 += bfhi(g6[0]); c2 += bflo(g6[1]); c3 += bfhi(g6[1]);
                c0 += bflo(g7[0]); c1 += bfhi(g7[0]); c2 += bflo(g7[1]); c3 += bfhi(g7[1]);
            }
            if (k < pv) {
                int4v q = *(const int4v*)(ip + k);
                uint2v g0 = *(const uint2v*)&hc[(q.x << 3) + (sub << 1)];
                uint2v g1 = *(const uint2v*)&hc[(q.y << 3) + (sub << 1)];
                uint2v g2 = *(const uint2v*)&hc[(q.z << 3) + (sub << 1)];
                uint2v g3 = *(const uint2v*)&hc[(q.w << 3) + (sub << 1)];
                a0 += bflo(g0[0]); a1 += bfhi(g0[0]); a2 += bflo(g0[1]); a3 += bfhi(g0[1]);
                a0 += bflo(g1[0]); a1 += bfhi(g1[0]); a2 += bflo(g1[1]); a3 += bfhi(g1[1]);
                a0 += bflo(g2[0]); a1 += bfhi(g2[0]); a2 += bflo(g2[1]); a3 += bfhi(g2[1]);
                a0 += bflo(g3[0]); a1 += bfhi(g3[0]); a2 += bflo(g3[1]); a3 += bfhi(g3[1]);
            }
        } else {
            const unsigned* gp = csr4 + m.z;
            for (int k = 0; k < pv; k += 4) {
                int4v q = *(const int4v*)(gp + k);
                uint2v g0 = *(const uint2v*)&hc[(q.x << 3) + (sub << 1)];
                uint2v g1 = *(const uint2v*)&hc[(q.y << 3) + (sub << 1)];
                uint2v g2 = *(const uint2v*)&hc[(q.z << 3) + (sub << 1)];
                uint2v g3 = *(const uint2v*)&hc[(q.w << 3) + (sub << 1)];
                a0 += bflo(g0[0]); a1 += bfhi(g0[0]); a2 += bflo(g0[1]); a3 += bfhi(g0[1]);
                a0 += bflo(g1[0]); a1 += bfhi(g1[0]); a2 += bflo(g1[1]); a3 += bfhi(g1[1]);
                a0 += bflo(g2[0]); a1 += bfhi(g2[0]); a2 += bflo(g2[1]); a3 += bfhi(g2[1]);
                a0 += bflo(g3[0]); a1 += bfhi(g3[0]); a2 += bflo(g3[1]); a3 += bfhi(g3[1]);
            }
        }
        if (node >= 0) {
            float di = rsqrtf((float)(v + 1));
            a0 += c0; a1 += c1; a2 += c2; a3 += c3;
            f32x4 o;
            o[0] = a0 * di + bb[0];
            o[1] = a1 * di + bb[1];
            o[2] = a2 * di + bb[2];
            o[3] = a3 * di + bb[3];
            __builtin_nontemporal_store(o, (f32x4*)&out[(size_t)node * 64 + chunk * 16 + sub * 4]);
        }
        cur ^= 1;
    }
}

extern "C" void kernel_launch(void* const* d_in, const int* in_sizes, int n_in,
                              void* d_out, int out_size, void* d_ws, size_t ws_size,
                              hipStream_t stream) {
    const float* x  = (const float*)d_in[0];
    const int*   ei = (const int*)d_in[1];
    const float* W1 = (const float*)d_in[2];
    const float* b1 = (const float*)d_in[3];
    const float* W2 = (const float*)d_in[4];
    const float* b2 = (const float*)d_in[5];
    float* out = (float*)d_out;

    const int N = in_sizes[0] / 128;
    const int E = in_sizes[1] / 2;
    const int* src = ei;
    const int* dst = ei + E;
    const int nbuck = (N + BSIZE - 1) >> BSHIFT;        // 196 for N=100000
    const int nslot = nbuck << BSHIFT;                  // rank slots (mult of 512)
    const int ngroups = nslot >> 6;                     // 64-slot groups (1568)
    const size_t capE = (size_t)nbuck << CAPSH;         // padded edge capacity
    const size_t np1 = (size_t)N + 1;

    float* dinv     = (float*)d_ws;                     // N
    int*   bcur     = (int*)(dinv + N);                 // 256
    int4v* meta4    = (int4v*)(bcur + 256);             // nslot {node,deg,rp,0}
    short* w1t      = (short*)(meta4 + nslot);          // 128*128
    short* w2t      = w1t + 128 * 128;                  // 64*128
    unsigned* csr4  = (unsigned*)(w2t + 64 * 128);      // capE (12.8 MB)
    short* bufH     = (short*)(csr4 + capE);            // 8*(N+1)*16 bf16 (h1')
    short* bufH2    = bufH + 8 * np1 * 16;              // 4*(N+1)*16 bf16 (h2')
    unsigned* aggb  = (unsigned*)(bufH2 + 4 * np1 * 16); // 8*(N+1)*8 bf16x2 (agg1)
    unsigned* ebuf  = aggb;                             // capE uints; aliases aggb
                                                        // (ebuf dead before pull128
                                                        //  writes aggb)

    const int ntile = (E + 4095) / 4096;

    // persistent-block slice counts (keep groups/block within LDS meta caps)
    int nbsl1 = 192;
    if ((ngroups + nbsl1 - 1) / nbsl1 > MAXG128) nbsl1 = (ngroups + MAXG128 - 1) / MAXG128;
    int nbsl2 = 384;
    if ((ngroups + nbsl2 - 1) / nbsl2 > MAXG64)  nbsl2 = (ngroups + MAXG64 - 1) / MAXG64;

    // ---- weight prep + bucket cursor init + ZROW zeroing ----
    k_prep<<<97, 256, 0, stream>>>(W1, W2, w1t, w2t, bcur, nbuck, bufH, bufH2, N);

    // ---- bucketed CSR build (degree-sorted, self+pad folded in) ----
    k_bucket<<<ntile, 256, 0, stream>>>(src, dst, bcur, ebuf, E, nbuck);
    k_bcsr<<<nbuck, BSIZE, 0, stream>>>(ebuf, bcur, dinv, meta4, csr4, N);

    // ---- layer 1 ----
    k_gemm1<<<(N + 63) / 64, 256, 0, stream>>>(x, w1t, dinv, bufH, N);
    k_pull128<<<8 * nbsl1, 256, 0, stream>>>((const unsigned*)bufH, meta4, csr4, aggb, N, ngroups);

    // ---- layer 2 ----
    k_gemm2<<<(N + 63) / 64, 256, 0, stream>>>(aggb, b1, w2t, dinv, bufH2, N);
    k_pull64<<<4 * nbsl2, 256, 0, stream>>>((const unsigned*)bufH2, meta4, csr4, b2, out, N, ngroups);
}

// Round 9
// 307.277 us; speedup vs baseline: 1.1313x; 1.1313x over previous
//
#include <hip/hip_runtime.h>
#include <hip/hip_bf16.h>

// GCN 2-layer forward, fp32 I/O. dinv folded into stored rows:
//   h1' = dinv * (x @ W1),  agg1 = dinv * (h1'[i] + sum_nbr h1'[s])
//   h2' = dinv * (relu(agg1+b1) @ W2),  out = dinv * (h2'[i] + sum h2'[s]) + b2
// so pull kernels are pure gather+add (no per-edge norm, no dinv reads).
// Packed 4B edge records; fixed-capacity bucketed CSR build with all
// per-node atomics in LDS; bf16 h/agg storage; MFMA bf16 GEMMs.
//
// ROUND 9 (= round-8 resubmission: bench failed on GPU acquisition, no
// data): round-0 row-major design (best measured, 60 us pull128 at the
// ~3.7 TB/s random-256B fabric roofline; six chunked-gather schedules all
// floored at >=90 us). Low-risk deltas vs round 0:
//  * NT loads on single-use streams (edge list, x) - keep L2 for h tables.
//    (x NT load via ext_vector f32x4, not HIP float4 struct.)
//  * NT stores for aggb/out - no write-allocate eviction of the gather
//    table during the two pull kernels.
// Pipeline:
//  1) k_prep: W1,W2 -> bf16 transposed; bcur[b] = b*CAP
//  2) k_bucket: partition packed {src,dloc} by dst>>9 into ebuf
//  3) k_bcsr:  per-bucket LDS stage -> hist -> scan -> deg/dinv/row_ptr
//              -> LDS-cursor scatter -> csr4 = src
//  4) h1' = dinv*(x @ W1) -> bf16                  (k_gemm1, MFMA)
//  5) aggb = dinv*(self+gather-sum of h1') -> bf16 (k_pull128)
//  6) h2' = dinv*(relu(aggb+b1) @ W2) -> bf16      (k_gemm2, MFMA)
//  7) out = dinv*(self+gather-sum of h2') + b2     (k_pull64)

typedef short short8v __attribute__((ext_vector_type(8)));   // 8 bf16 (4 VGPRs)
typedef float f32x4   __attribute__((ext_vector_type(4)));   // MFMA acc / NT loads

#define BSHIFT 9           // bucket = dst >> 9 (span 512 nodes)
#define BSIZE  512
#define CAPSH  14          // per-bucket capacity 16384 (mean 8163, >40 sigma)
#define CAP    (1 << CAPSH)

// RNE fp32 -> bf16 (finite inputs)
__device__ __forceinline__ short f2bf(float f) {
    unsigned u = __float_as_uint(f);
    return (short)((u + 0x7fffu + ((u >> 16) & 1u)) >> 16);
}
__device__ __forceinline__ unsigned pack2bf(float a, float b) {
    return (unsigned)(unsigned short)f2bf(a) | ((unsigned)(unsigned short)f2bf(b) << 16);
}
__device__ __forceinline__ float bflo(unsigned u) { return __uint_as_float(u << 16); }
__device__ __forceinline__ float bfhi(unsigned u) { return __uint_as_float(u & 0xffff0000u); }

// ---- W prep + bucket-cursor init (one launch) ----
__global__ void k_prep(const float* __restrict__ W1, const float* __restrict__ W2,
                       short* __restrict__ w1t, short* __restrict__ w2t,
                       int* __restrict__ bcur, int nbuck) {
    int b = blockIdx.x;
    int t = threadIdx.x;
    if (b == gridDim.x - 1) {                 // last block: init bucket cursors
        if (t < nbuck) bcur[t] = t << CAPSH;
        return;
    }
    int i = b * 256 + t;                      // 96 blocks cover 24576 elems
    if (i < 128 * 128) {
        int n = i >> 7, k = i & 127;
        w1t[i] = f2bf(W1[k * 128 + n]);
    } else {
        int j = i - 128 * 128;
        int n = j >> 7, k = j & 127;
        w2t[j] = f2bf(W2[k * 64 + n]);
    }
}

// ---- partition edges into packed ebuf: entry = (src<<9) | (dst&511) ----
__global__ __launch_bounds__(256) void k_bucket(const int* __restrict__ src,
                                                const int* __restrict__ dst,
                                                int* __restrict__ bcur,
                                                unsigned* __restrict__ ebuf,
                                                int E, int nbuck) {
    __shared__ int sdst[4096];
    __shared__ int ssrc[4096];
    __shared__ int hist[256];
    __shared__ int base[256];
    int t = threadIdx.x;
    int e0 = blockIdx.x * 4096;
    for (int i = t; i < nbuck; i += 256) hist[i] = 0;
    for (int i = 0; i < 16; ++i) {                  // single global read (NT: stream)
        int k = i * 256 + t;
        int e = e0 + k;
        sdst[k] = (e < E) ? __builtin_nontemporal_load(&dst[e]) : -1;
        ssrc[k] = (e < E) ? __builtin_nontemporal_load(&src[e]) : 0;
    }
    __syncthreads();
    for (int i = 0; i < 16; ++i) {                  // pass 1: LDS histogram
        int d = sdst[i * 256 + t];
        if (d >= 0) atomicAdd(&hist[d >> BSHIFT], 1);
    }
    __syncthreads();
    for (int b = t; b < nbuck; b += 256) {          // pass 2: reserve chunks
        int c = hist[b];
        base[b] = c ? atomicAdd(&bcur[b], c) : 0;
        hist[b] = 0;
    }
    __syncthreads();
    for (int i = 0; i < 16; ++i) {                  // pass 3: grouped writes
        int k = i * 256 + t;
        int d = sdst[k];
        if (d >= 0) {
            int bk = d >> BSHIFT;
            int off = atomicAdd(&hist[bk], 1);
            ebuf[base[bk] + off] = ((unsigned)ssrc[k] << BSHIFT) | (unsigned)(d & (BSIZE - 1));
        }
    }
}

// ---- per-bucket merged: LDS stage -> hist -> scan -> deg/dinv/row_ptr
//      -> LDS-cursor scatter -> csr4 = src ----
__global__ __launch_bounds__(BSIZE) void k_bcsr(const unsigned* __restrict__ ebuf,
                                                const int* __restrict__ bcur,
                                                int* __restrict__ deg,
                                                int* __restrict__ row_ptr,
                                                float* __restrict__ dinv,
                                                unsigned* __restrict__ csr4, int n) {
    __shared__ unsigned edges[CAP];    // 64 KB
    __shared__ int hist[BSIZE];
    __shared__ int s[BSIZE];
    __shared__ int cur[BSIZE];
    int b = blockIdx.x;
    int t = threadIdx.x;
    hist[t] = 0;
    __syncthreads();
    int base = b << CAPSH;
    int cnt  = bcur[b] - base;
    int lo = b << BSHIFT;
    for (int k = t; k < cnt; k += BSIZE) {          // stage + LDS hist
        unsigned e = ebuf[base + k];
        edges[k] = e;
        atomicAdd(&hist[e & (BSIZE - 1)], 1);
    }
    __syncthreads();
    int v = hist[t];
    s[t] = v;
    __syncthreads();
    for (int off = 1; off < BSIZE; off <<= 1) {     // inclusive scan
        int add = (t >= off) ? s[t - off] : 0;
        __syncthreads();
        s[t] += add;
        __syncthreads();
    }
    int rp = base + s[t] - v;                       // padded-CSR offset
    cur[t] = rp;
    int node = lo + t;
    if (node < n) {
        deg[node]     = v;
        row_ptr[node] = rp;
        dinv[node]    = rsqrtf((float)(v + 1));
    }
    __syncthreads();
    for (int k = t; k < cnt; k += BSIZE) {          // scatter src -> csr4
        unsigned e = edges[k];
        int pos = atomicAdd(&cur[e & (BSIZE - 1)], 1);
        csr4[pos] = e >> BSHIFT;
    }
}

// ---- MFMA GEMM1: h1'[64rows,128] = dinv*(bf16(x) @ bf16(W1)) ----
#define LDP 136
__global__ __launch_bounds__(256) void k_gemm1(const float* __restrict__ x,
                                               const short* __restrict__ w1t,
                                               const float* __restrict__ dinv,
                                               short* __restrict__ h, int nrows) {
    __shared__ short xs[64 * LDP];
    __shared__ short wt[128 * LDP];
    int t = threadIdx.x;
    int row0 = blockIdx.x * 64;
    for (int i = 0; i < 16; ++i) {
        int idx = t + i * 256;
        int r = idx >> 5, c4 = idx & 31;
        f32x4 v = {0.f, 0.f, 0.f, 0.f};
        if (row0 + r < nrows) {
            const f32x4* px = (const f32x4*)x + (size_t)(row0 + r) * 32 + c4;
            v = __builtin_nontemporal_load(px);     // x read once: NT (ext-vector)
        }
        short4 o = make_short4(f2bf(v[0]), f2bf(v[1]), f2bf(v[2]), f2bf(v[3]));
        *(short4*)&xs[r * LDP + c4 * 4] = o;
    }
    for (int i = 0; i < 16; ++i) {
        int idx = t + i * 256;
        int n = idx >> 5, c4 = idx & 31;
        *(short4*)&wt[n * LDP + c4 * 4] = ((const short4*)w1t)[idx];
    }
    __syncthreads();
    int wave = t >> 6, lane = t & 63;
    int quad = lane >> 4, c = lane & 15;
    int m0 = wave * 16;
    f32x4 acc[8] = {};
    #pragma unroll
    for (int kc = 0; kc < 4; ++kc) {
        short8v a = *(const short8v*)&xs[(m0 + c) * LDP + kc * 32 + quad * 8];
        #pragma unroll
        for (int nt = 0; nt < 8; ++nt) {
            short8v b = *(const short8v*)&wt[(nt * 16 + c) * LDP + kc * 32 + quad * 8];
            acc[nt] = __builtin_amdgcn_mfma_f32_16x16x32_bf16(a, b, acc[nt], 0, 0, 0);
        }
    }
    #pragma unroll
    for (int r = 0; r < 4; ++r) {
        int row = row0 + m0 + quad * 4 + r;
        if (row < nrows) {
            float dr = dinv[row];                   // fold norm into stored row
            #pragma unroll
            for (int nt = 0; nt < 8; ++nt)
                h[(size_t)row * 128 + nt * 16 + c] = f2bf(acc[nt][r] * dr);
        }
    }
}

// ---- MFMA GEMM2: h2'[64rows,64] = dinv*(bf16(relu(aggb+b1)) @ bf16(W2)) ----
__global__ __launch_bounds__(256) void k_gemm2(const unsigned* __restrict__ aggb, // bf16x2
                                               const float* __restrict__ b1,
                                               const short* __restrict__ w2t,
                                               const float* __restrict__ dinv,
                                               short* __restrict__ h2, int nrows) {
    __shared__ short xs[64 * LDP];
    __shared__ short wt[64 * LDP];
    int t = threadIdx.x;
    int row0 = blockIdx.x * 64;
    for (int i = 0; i < 16; ++i) {                    // 64 rows x 64 bf16-pairs
        int idx = t + i * 256;
        int r = idx >> 6, cp = idx & 63;
        unsigned o = 0;
        if (row0 + r < nrows) {
            unsigned u = aggb[(size_t)(row0 + r) * 64 + cp];
            float2 bb = ((const float2*)b1)[cp];
            float vx = fmaxf(bflo(u) + bb.x, 0.f);
            float vy = fmaxf(bfhi(u) + bb.y, 0.f);
            o = pack2bf(vx, vy);
        }
        *(unsigned*)&xs[r * LDP + cp * 2] = o;
    }
    for (int i = 0; i < 8; ++i) {
        int idx = t + i * 256;
        int n = idx >> 5, c4 = idx & 31;
        *(short4*)&wt[n * LDP + c4 * 4] = ((const short4*)w2t)[idx];
    }
    __syncthreads();
    int wave = t >> 6, lane = t & 63;
    int quad = lane >> 4, c = lane & 15;
    int m0 = wave * 16;
    f32x4 acc[4] = {};
    #pragma unroll
    for (int kc = 0; kc < 4; ++kc) {
        short8v av = *(const short8v*)&xs[(m0 + c) * LDP + kc * 32 + quad * 8];
        #pragma unroll
        for (int nt = 0; nt < 4; ++nt) {
            short8v b = *(const short8v*)&wt[(nt * 16 + c) * LDP + kc * 32 + quad * 8];
            acc[nt] = __builtin_amdgcn_mfma_f32_16x16x32_bf16(av, b, acc[nt], 0, 0, 0);
        }
    }
    #pragma unroll
    for (int r = 0; r < 4; ++r) {
        int row = row0 + m0 + quad * 4 + r;
        if (row < nrows) {
            float dr = dinv[row];
            #pragma unroll
            for (int nt = 0; nt < 4; ++nt)
                h2[(size_t)row * 64 + nt * 16 + c] = f2bf(acc[nt][r] * dr);
        }
    }
}

// pull 128 feats: aggb[i] = bf16( dinv[i] * (h'[i] + sum_nbr h'[s]) ).
// One wave/node; pure gather+add inner loop (csr reads on scalar path).
__global__ __launch_bounds__(256) void k_pull128(const unsigned short* __restrict__ h,
                                                 const int* __restrict__ row_ptr,
                                                 const int* __restrict__ deg,
                                                 const unsigned* __restrict__ csr4,
                                                 const float* __restrict__ dinv,
                                                 unsigned* __restrict__ aggb, int n) {
    int wave = (blockIdx.x * 256 + threadIdx.x) >> 6;
    int lane = threadIdx.x & 63;
    if (wave >= n) return;
    int i = __builtin_amdgcn_readfirstlane(wave);
    float2 acc;
    {
        unsigned u = ((const unsigned*)(h + (size_t)i * 128))[lane];   // self
        acc.x = bflo(u);
        acc.y = bfhi(u);
    }
    int beg = row_ptr[i];
    int cnt = deg[i];
    int k = 0;
    for (; k + 8 <= cnt; k += 8) {
        unsigned sid[8];
        unsigned g[8];
        #pragma unroll
        for (int j = 0; j < 8; ++j) sid[j] = csr4[beg + k + j];
        #pragma unroll
        for (int j = 0; j < 8; ++j)
            g[j] = ((const unsigned*)(h + (size_t)sid[j] * 128))[lane];
        #pragma unroll
        for (int j = 0; j < 8; ++j) {
            acc.x += bflo(g[j]);
            acc.y += bfhi(g[j]);
        }
    }
    for (; k < cnt; ++k) {
        unsigned sid = csr4[beg + k];
        unsigned g = ((const unsigned*)(h + (size_t)sid * 128))[lane];
        acc.x += bflo(g);
        acc.y += bfhi(g);
    }
    float di = dinv[i];
    // NT store: don't write-allocate aggb in L2 (protect h table residency)
    __builtin_nontemporal_store(pack2bf(acc.x * di, acc.y * di),
                                &aggb[(size_t)i * 64 + lane]);
}

// pull 64 feats: out[i] = dinv[i]*(h'[i] + sum h'[s]) + b2. One wave/node.
__global__ __launch_bounds__(256) void k_pull64(const unsigned short* __restrict__ h,
                                                const int* __restrict__ row_ptr,
                                                const int* __restrict__ deg,
                                                const unsigned* __restrict__ csr4,
                                                const float* __restrict__ dinv,
                                                const float* __restrict__ b2,
                                                float* __restrict__ out, int n) {
    int wave = (blockIdx.x * 256 + threadIdx.x) >> 6;
    int lane = threadIdx.x & 63;
    if (wave >= n) return;
    int i = __builtin_amdgcn_readfirstlane(wave);
    float acc = __uint_as_float((unsigned)h[(size_t)i * 64 + lane] << 16);  // self
    int beg = row_ptr[i];
    int cnt = deg[i];
    int k = 0;
    for (; k + 8 <= cnt; k += 8) {
        unsigned sid[8];
        unsigned short u[8];
        #pragma unroll
        for (int j = 0; j < 8; ++j) sid[j] = csr4[beg + k + j];
        #pragma unroll
        for (int j = 0; j < 8; ++j) u[j] = h[(size_t)sid[j] * 64 + lane];
        #pragma unroll
        for (int j = 0; j < 8; ++j)
            acc += __uint_as_float((unsigned)u[j] << 16);
    }
    for (; k < cnt; ++k) {
        unsigned sid = csr4[beg + k];
        acc += __uint_as_float((unsigned)h[(size_t)sid * 64 + lane] << 16);
    }
    // NT store: final output, never re-read on device
    __builtin_nontemporal_store(acc * dinv[i] + b2[lane],
                                &out[(size_t)i * 64 + lane]);
}

extern "C" void kernel_launch(void* const* d_in, const int* in_sizes, int n_in,
                              void* d_out, int out_size, void* d_ws, size_t ws_size,
                              hipStream_t stream) {
    const float* x  = (const float*)d_in[0];
    const int*   ei = (const int*)d_in[1];
    const float* W1 = (const float*)d_in[2];
    const float* b1 = (const float*)d_in[3];
    const float* W2 = (const float*)d_in[4];
    const float* b2 = (const float*)d_in[5];
    float* out = (float*)d_out;

    const int N = in_sizes[0] / 128;
    const int E = in_sizes[1] / 2;
    const int* src = ei;
    const int* dst = ei + E;
    const int nbuck = (N + BSIZE - 1) >> BSHIFT;        // 196 for N=100000
    const size_t capE = (size_t)nbuck << CAPSH;         // padded edge capacity

    float* dinv     = (float*)d_ws;                     // N
    int*   deg      = (int*)(dinv + N);                 // N
    int*   row_ptr  = deg + N;                          // N
    int*   bcur     = row_ptr + N;                      // 256
    short* w1t      = (short*)(bcur + 256);             // 128*128
    short* w2t      = w1t + 128 * 128;                  // 64*128
    unsigned* csr4  = (unsigned*)(w2t + 64 * 128);      // capE (12.8 MB)
    short* bufH     = (short*)(csr4 + capE);            // N*128 bf16 (h1')
    short* bufH2    = bufH + (size_t)N * 128;           // N*64  bf16 (h2')
    unsigned* aggb  = (unsigned*)(bufH2 + (size_t)N * 64); // N*64 bf16x2 (agg1)
    unsigned* ebuf  = (unsigned*)bufH2;                 // capE uints; aliases
                                                        // bufH2+aggb (ebuf dead
                                                        // before their writes)

    const int ntile = (E + 4095) / 4096;

    // ---- weight prep + bucket cursor init ----
    k_prep<<<97, 256, 0, stream>>>(W1, W2, w1t, w2t, bcur, nbuck);

    // ---- bucketed CSR build (per-node atomics all in LDS) ----
    k_bucket<<<ntile, 256, 0, stream>>>(src, dst, bcur, ebuf, E, nbuck);
    k_bcsr<<<nbuck, BSIZE, 0, stream>>>(ebuf, bcur, deg, row_ptr, dinv, csr4, N);

    // ---- layer 1 ----
    k_gemm1<<<(N + 63) / 64, 256, 0, stream>>>(x, w1t, dinv, bufH, N);
    k_pull128<<<(N + 3) / 4, 256, 0, stream>>>((const unsigned short*)bufH, row_ptr, deg, csr4, dinv, aggb, N);

    // ---- layer 2 ----
    k_gemm2<<<(N + 63) / 64, 256, 0, stream>>>(aggb, b1, w2t, dinv, bufH2, N);
    k_pull64<<<(N + 3) / 4, 256, 0, stream>>>((const unsigned short*)bufH2, row_ptr, deg, csr4, dinv, b2, out, N);
}

// Round 12
// 285.690 us; speedup vs baseline: 1.2167x; 1.0756x over previous
//
#include <hip/hip_runtime.h>
#include <hip/hip_bf16.h>

// GCN 2-layer forward, fp32 I/O. dinv folded into stored rows:
//   h1' = dinv * (x @ W1),  agg1 = dinv * (h1'[i] + sum_nbr h1'[s])
//   h2' = dinv * (relu(agg1+b1) @ W2),  out = dinv * (h2'[i] + sum h2'[s]) + b2
// so pull kernels are pure gather+add (no per-edge norm, no dinv reads).
// Packed 4B edge records; fixed-capacity bucketed CSR build with all
// per-node atomics in LDS; bf16 h/agg storage; MFMA bf16 GEMMs.
//
// ROUND 12 (= round-10/11 resubmission: benches failed on GPU
// acquisition, no data). Round-9 post-mortem showed the NT-hint bundle
// regressed the total (+15 us) while pull128 stayed at its 60 us floor;
// the aggb NT store forced gemm2 to HBM-fetch its input (25.6 MB
// re-read). Reverted all NT hints except the final `out` store (never
// re-read).
// ONE experiment: k_pull64 now processes TWO nodes per wave (32-lane
// half-waves, uint granule) -> each gather instruction covers 2 rows
// (256 B), 2x rows in flight per wave; helps if pull64 is issue-limited.
// pull128 is at its random-256B fabric roofline (FETCH == compulsory
// floor, 3.75 TB/s) and is left untouched.
// Pipeline:
//  1) k_prep: W1,W2 -> bf16 transposed; bcur[b] = b*CAP
//  2) k_bucket: partition packed {src,dloc} by dst>>9 into ebuf
//  3) k_bcsr:  per-bucket LDS stage -> hist -> scan -> deg/dinv/row_ptr
//              -> LDS-cursor scatter -> csr4 = src
//  4) h1' = dinv*(x @ W1) -> bf16                  (k_gemm1, MFMA)
//  5) aggb = dinv*(self+gather-sum of h1') -> bf16 (k_pull128)
//  6) h2' = dinv*(relu(aggb+b1) @ W2) -> bf16      (k_gemm2, MFMA)
//  7) out = dinv*(self+gather-sum of h2') + b2     (k_pull64, 2 nodes/wave)

typedef short short8v __attribute__((ext_vector_type(8)));   // 8 bf16 (4 VGPRs)
typedef float f32x4   __attribute__((ext_vector_type(4)));   // MFMA acc
typedef float f32x2   __attribute__((ext_vector_type(2)));   // NT out store

#define BSHIFT 9           // bucket = dst >> 9 (span 512 nodes)
#define BSIZE  512
#define CAPSH  14          // per-bucket capacity 16384 (mean 8163, >40 sigma)
#define CAP    (1 << CAPSH)

// RNE fp32 -> bf16 (finite inputs)
__device__ __forceinline__ short f2bf(float f) {
    unsigned u = __float_as_uint(f);
    return (short)((u + 0x7fffu + ((u >> 16) & 1u)) >> 16);
}
__device__ __forceinline__ unsigned pack2bf(float a, float b) {
    return (unsigned)(unsigned short)f2bf(a) | ((unsigned)(unsigned short)f2bf(b) << 16);
}
__device__ __forceinline__ float bflo(unsigned u) { return __uint_as_float(u << 16); }
__device__ __forceinline__ float bfhi(unsigned u) { return __uint_as_float(u & 0xffff0000u); }

// ---- W prep + bucket-cursor init (one launch) ----
__global__ void k_prep(const float* __restrict__ W1, const float* __restrict__ W2,
                       short* __restrict__ w1t, short* __restrict__ w2t,
                       int* __restrict__ bcur, int nbuck) {
    int b = blockIdx.x;
    int t = threadIdx.x;
    if (b == gridDim.x - 1) {                 // last block: init bucket cursors
        if (t < nbuck) bcur[t] = t << CAPSH;
        return;
    }
    int i = b * 256 + t;                      // 96 blocks cover 24576 elems
    if (i < 128 * 128) {
        int n = i >> 7, k = i & 127;
        w1t[i] = f2bf(W1[k * 128 + n]);
    } else {
        int j = i - 128 * 128;
        int n = j >> 7, k = j & 127;
        w2t[j] = f2bf(W2[k * 64 + n]);
    }
}

// ---- partition edges into packed ebuf: entry = (src<<9) | (dst&511) ----
__global__ __launch_bounds__(256) void k_bucket(const int* __restrict__ src,
                                                const int* __restrict__ dst,
                                                int* __restrict__ bcur,
                                                unsigned* __restrict__ ebuf,
                                                int E, int nbuck) {
    __shared__ int sdst[4096];
    __shared__ int ssrc[4096];
    __shared__ int hist[256];
    __shared__ int base[256];
    int t = threadIdx.x;
    int e0 = blockIdx.x * 4096;
    for (int i = t; i < nbuck; i += 256) hist[i] = 0;
    for (int i = 0; i < 16; ++i) {                  // single global read
        int k = i * 256 + t;
        int e = e0 + k;
        sdst[k] = (e < E) ? dst[e] : -1;
        ssrc[k] = (e < E) ? src[e] : 0;
    }
    __syncthreads();
    for (int i = 0; i < 16; ++i) {                  // pass 1: LDS histogram
        int d = sdst[i * 256 + t];
        if (d >= 0) atomicAdd(&hist[d >> BSHIFT], 1);
    }
    __syncthreads();
    for (int b = t; b < nbuck; b += 256) {          // pass 2: reserve chunks
        int c = hist[b];
        base[b] = c ? atomicAdd(&bcur[b], c) : 0;
        hist[b] = 0;
    }
    __syncthreads();
    for (int i = 0; i < 16; ++i) {                  // pass 3: grouped writes
        int k = i * 256 + t;
        int d = sdst[k];
        if (d >= 0) {
            int bk = d >> BSHIFT;
            int off = atomicAdd(&hist[bk], 1);
            ebuf[base[bk] + off] = ((unsigned)ssrc[k] << BSHIFT) | (unsigned)(d & (BSIZE - 1));
        }
    }
}

// ---- per-bucket merged: LDS stage -> hist -> scan -> deg/dinv/row_ptr
//      -> LDS-cursor scatter -> csr4 = src ----
__global__ __launch_bounds__(BSIZE) void k_bcsr(const unsigned* __restrict__ ebuf,
                                                const int* __restrict__ bcur,
                                                int* __restrict__ deg,
                                                int* __restrict__ row_ptr,
                                                float* __restrict__ dinv,
                                                unsigned* __restrict__ csr4, int n) {
    __shared__ unsigned edges[CAP];    // 64 KB
    __shared__ int hist[BSIZE];
    __shared__ int s[BSIZE];
    __shared__ int cur[BSIZE];
    int b = blockIdx.x;
    int t = threadIdx.x;
    hist[t] = 0;
    __syncthreads();
    int base = b << CAPSH;
    int cnt  = bcur[b] - base;
    int lo = b << BSHIFT;
    for (int k = t; k < cnt; k += BSIZE) {          // stage + LDS hist
        unsigned e = ebuf[base + k];
        edges[k] = e;
        atomicAdd(&hist[e & (BSIZE - 1)], 1);
    }
    __syncthreads();
    int v = hist[t];
    s[t] = v;
    __syncthreads();
    for (int off = 1; off < BSIZE; off <<= 1) {     // inclusive scan
        int add = (t >= off) ? s[t - off] : 0;
        __syncthreads();
        s[t] += add;
        __syncthreads();
    }
    int rp = base + s[t] - v;                       // padded-CSR offset
    cur[t] = rp;
    int node = lo + t;
    if (node < n) {
        deg[node]     = v;
        row_ptr[node] = rp;
        dinv[node]    = rsqrtf((float)(v + 1));
    }
    __syncthreads();
    for (int k = t; k < cnt; k += BSIZE) {          // scatter src -> csr4
        unsigned e = edges[k];
        int pos = atomicAdd(&cur[e & (BSIZE - 1)], 1);
        csr4[pos] = e >> BSHIFT;
    }
}

// ---- MFMA GEMM1: h1'[64rows,128] = dinv*(bf16(x) @ bf16(W1)) ----
#define LDP 136
__global__ __launch_bounds__(256) void k_gemm1(const float* __restrict__ x,
                                               const short* __restrict__ w1t,
                                               const float* __restrict__ dinv,
                                               short* __restrict__ h, int nrows) {
    __shared__ short xs[64 * LDP];
    __shared__ short wt[128 * LDP];
    int t = threadIdx.x;
    int row0 = blockIdx.x * 64;
    for (int i = 0; i < 16; ++i) {
        int idx = t + i * 256;
        int r = idx >> 5, c4 = idx & 31;
        float4 v = make_float4(0.f, 0.f, 0.f, 0.f);
        if (row0 + r < nrows) v = ((const float4*)x)[(size_t)(row0 + r) * 32 + c4];
        short4 o = make_short4(f2bf(v.x), f2bf(v.y), f2bf(v.z), f2bf(v.w));
        *(short4*)&xs[r * LDP + c4 * 4] = o;
    }
    for (int i = 0; i < 16; ++i) {
        int idx = t + i * 256;
        int n = idx >> 5, c4 = idx & 31;
        *(short4*)&wt[n * LDP + c4 * 4] = ((const short4*)w1t)[idx];
    }
    __syncthreads();
    int wave = t >> 6, lane = t & 63;
    int quad = lane >> 4, c = lane & 15;
    int m0 = wave * 16;
    f32x4 acc[8] = {};
    #pragma unroll
    for (int kc = 0; kc < 4; ++kc) {
        short8v a = *(const short8v*)&xs[(m0 + c) * LDP + kc * 32 + quad * 8];
        #pragma unroll
        for (int nt = 0; nt < 8; ++nt) {
            short8v b = *(const short8v*)&wt[(nt * 16 + c) * LDP + kc * 32 + quad * 8];
            acc[nt] = __builtin_amdgcn_mfma_f32_16x16x32_bf16(a, b, acc[nt], 0, 0, 0);
        }
    }
    #pragma unroll
    for (int r = 0; r < 4; ++r) {
        int row = row0 + m0 + quad * 4 + r;
        if (row < nrows) {
            float dr = dinv[row];                   // fold norm into stored row
            #pragma unroll
            for (int nt = 0; nt < 8; ++nt)
                h[(size_t)row * 128 + nt * 16 + c] = f2bf(acc[nt][r] * dr);
        }
    }
}

// ---- MFMA GEMM2: h2'[64rows,64] = dinv*(bf16(relu(aggb+b1)) @ bf16(W2)) ----
__global__ __launch_bounds__(256) void k_gemm2(const unsigned* __restrict__ aggb, // bf16x2
                                               const float* __restrict__ b1,
                                               const short* __restrict__ w2t,
                                               const float* __restrict__ dinv,
                                               short* __restrict__ h2, int nrows) {
    __shared__ short xs[64 * LDP];
    __shared__ short wt[64 * LDP];
    int t = threadIdx.x;
    int row0 = blockIdx.x * 64;
    for (int i = 0; i < 16; ++i) {                    // 64 rows x 64 bf16-pairs
        int idx = t + i * 256;
        int r = idx >> 6, cp = idx & 63;
        unsigned o = 0;
        if (row0 + r < nrows) {
            unsigned u = aggb[(size_t)(row0 + r) * 64 + cp];
            float2 bb = ((const float2*)b1)[cp];
            float vx = fmaxf(bflo(u) + bb.x, 0.f);
            float vy = fmaxf(bfhi(u) + bb.y, 0.f);
            o = pack2bf(vx, vy);
        }
        *(unsigned*)&xs[r * LDP + cp * 2] = o;
    }
    for (int i = 0; i < 8; ++i) {
        int idx = t + i * 256;
        int n = idx >> 5, c4 = idx & 31;
        *(short4*)&wt[n * LDP + c4 * 4] = ((const short4*)w2t)[idx];
    }
    __syncthreads();
    int wave = t >> 6, lane = t & 63;
    int quad = lane >> 4, c = lane & 15;
    int m0 = wave * 16;
    f32x4 acc[4] = {};
    #pragma unroll
    for (int kc = 0; kc < 4; ++kc) {
        short8v av = *(const short8v*)&xs[(m0 + c) * LDP + kc * 32 + quad * 8];
        #pragma unroll
        for (int nt = 0; nt < 4; ++nt) {
            short8v b = *(const short8v*)&wt[(nt * 16 + c) * LDP + kc * 32 + quad * 8];
            acc[nt] = __builtin_amdgcn_mfma_f32_16x16x32_bf16(av, b, acc[nt], 0, 0, 0);
        }
    }
    #pragma unroll
    for (int r = 0; r < 4; ++r) {
        int row = row0 + m0 + quad * 4 + r;
        if (row < nrows) {
            float dr = dinv[row];
            #pragma unroll
            for (int nt = 0; nt < 4; ++nt)
                h2[(size_t)row * 64 + nt * 16 + c] = f2bf(acc[nt][r] * dr);
        }
    }
}

// pull 128 feats: aggb[i] = bf16( dinv[i] * (h'[i] + sum_nbr h'[s]) ).
// One wave/node; pure gather+add inner loop (csr reads on scalar path).
// At the random-256B fabric roofline (FETCH == compulsory floor) — unchanged.
__global__ __launch_bounds__(256) void k_pull128(const unsigned short* __restrict__ h,
                                                 const int* __restrict__ row_ptr,
                                                 const int* __restrict__ deg,
                                                 const unsigned* __restrict__ csr4,
                                                 const float* __restrict__ dinv,
                                                 unsigned* __restrict__ aggb, int n) {
    int wave = (blockIdx.x * 256 + threadIdx.x) >> 6;
    int lane = threadIdx.x & 63;
    if (wave >= n) return;
    int i = __builtin_amdgcn_readfirstlane(wave);
    float2 acc;
    {
        unsigned u = ((const unsigned*)(h + (size_t)i * 128))[lane];   // self
        acc.x = bflo(u);
        acc.y = bfhi(u);
    }
    int beg = row_ptr[i];
    int cnt = deg[i];
    int k = 0;
    for (; k + 8 <= cnt; k += 8) {
        unsigned sid[8];
        unsigned g[8];
        #pragma unroll
        for (int j = 0; j < 8; ++j) sid[j] = csr4[beg + k + j];
        #pragma unroll
        for (int j = 0; j < 8; ++j)
            g[j] = ((const unsigned*)(h + (size_t)sid[j] * 128))[lane];
        #pragma unroll
        for (int j = 0; j < 8; ++j) {
            acc.x += bflo(g[j]);
            acc.y += bfhi(g[j]);
        }
    }
    for (; k < cnt; ++k) {
        unsigned sid = csr4[beg + k];
        unsigned g = ((const unsigned*)(h + (size_t)sid * 128))[lane];
        acc.x += bflo(g);
        acc.y += bfhi(g);
    }
    float di = dinv[i];
    aggb[(size_t)i * 64 + lane] = pack2bf(acc.x * di, acc.y * di);   // plain store:
                                                                     // gemm2 re-reads
}

// pull 64 feats, TWO nodes per wave: 32-lane half-waves, uint granule.
// Each gather instruction covers 2 rows (2 x 128 B) -> 2x rows in flight.
// out[i] = dinv[i]*(h'[i] + sum h'[s]) + b2; NT store (never re-read).
__global__ __launch_bounds__(256) void k_pull64(const unsigned short* __restrict__ h,
                                                const int* __restrict__ row_ptr,
                                                const int* __restrict__ deg,
                                                const unsigned* __restrict__ csr4,
                                                const float* __restrict__ dinv,
                                                const float* __restrict__ b2,
                                                float* __restrict__ out, int n) {
    int wave = (blockIdx.x * 256 + threadIdx.x) >> 6;
    int lane = threadIdx.x & 63;
    int half = lane >> 5;                 // which of the wave's 2 nodes
    int lh   = lane & 31;                 // uint index: feats 2lh, 2lh+1
    int node = wave * 2 + half;
    bool alive = node < n;
    int nn = alive ? node : 0;            // safe row for dead half
    int beg = row_ptr[nn];
    int cnt = alive ? deg[nn] : 0;
    float2 acc;
    {
        unsigned u = ((const unsigned*)(h + (size_t)nn * 64))[lh];   // self (128B/half)
        acc.x = bflo(u);
        acc.y = bfhi(u);
    }
    int k = 0;
    for (; k + 8 <= cnt; k += 8) {        // per-half trip counts, exec-masked
        unsigned sid[8];
        unsigned g[8];
        #pragma unroll
        for (int j = 0; j < 8; ++j) sid[j] = csr4[beg + k + j];
        #pragma unroll
        for (int j = 0; j < 8; ++j)
            g[j] = ((const unsigned*)(h + (size_t)sid[j] * 64))[lh];
        #pragma unroll
        for (int j = 0; j < 8; ++j) {
            acc.x += bflo(g[j]);
            acc.y += bfhi(g[j]);
        }
    }
    for (; k < cnt; ++k) {
        unsigned sid = csr4[beg + k];
        unsigned g = ((const unsigned*)(h + (size_t)sid * 64))[lh];
        acc.x += bflo(g);
        acc.y += bfhi(g);
    }
    if (alive) {
        float di = dinv[nn];
        float2 bb = ((const float2*)b2)[lh];
        f32x2 o;
        o[0] = acc.x * di + bb.x;
        o[1] = acc.y * di + bb.y;
        __builtin_nontemporal_store(o, (f32x2*)&out[(size_t)nn * 64 + lh * 2]);
    }
}

extern "C" void kernel_launch(void* const* d_in, const int* in_sizes, int n_in,
                              void* d_out, int out_size, void* d_ws, size_t ws_size,
                              hipStream_t stream) {
    const float* x  = (const float*)d_in[0];
    const int*   ei = (const int*)d_in[1];
    const float* W1 = (const float*)d_in[2];
    const float* b1 = (const float*)d_in[3];
    const float* W2 = (const float*)d_in[4];
    const float* b2 = (const float*)d_in[5];
    float* out = (float*)d_out;

    const int N = in_sizes[0] / 128;
    const int E = in_sizes[1] / 2;
    const int* src = ei;
    const int* dst = ei + E;
    const int nbuck = (N + BSIZE - 1) >> BSHIFT;        // 196 for N=100000
    const size_t capE = (size_t)nbuck << CAPSH;         // padded edge capacity

    float* dinv     = (float*)d_ws;                     // N
    int*   deg      = (int*)(dinv + N);                 // N
    int*   row_ptr  = deg + N;                          // N
    int*   bcur     = row_ptr + N;                      // 256
    short* w1t      = (short*)(bcur + 256);             // 128*128
    short* w2t      = w1t + 128 * 128;                  // 64*128
    unsigned* csr4  = (unsigned*)(w2t + 64 * 128);      // capE (12.8 MB)
    short* bufH     = (short*)(csr4 + capE);            // N*128 bf16 (h1')
    short* bufH2    = bufH + (size_t)N * 128;           // N*64  bf16 (h2')
    unsigned* aggb  = (unsigned*)(bufH2 + (size_t)N * 64); // N*64 bf16x2 (agg1)
    unsigned* ebuf  = (unsigned*)bufH2;                 // capE uints; aliases
                                                        // bufH2+aggb (ebuf dead
                                                        // before their writes)

    const int ntile = (E + 4095) / 4096;
    const int nwv64 = (N + 1) / 2;                      // pull64 waves (2 nodes each)

    // ---- weight prep + bucket cursor init ----
    k_prep<<<97, 256, 0, stream>>>(W1, W2, w1t, w2t, bcur, nbuck);

    // ---- bucketed CSR build (per-node atomics all in LDS) ----
    k_bucket<<<ntile, 256, 0, stream>>>(src, dst, bcur, ebuf, E, nbuck);
    k_bcsr<<<nbuck, BSIZE, 0, stream>>>(ebuf, bcur, deg, row_ptr, dinv, csr4, N);

    // ---- layer 1 ----
    k_gemm1<<<(N + 63) / 64, 256, 0, stream>>>(x, w1t, dinv, bufH, N);
    k_pull128<<<(N + 3) / 4, 256, 0, stream>>>((const unsigned short*)bufH, row_ptr, deg, csr4, dinv, aggb, N);

    // ---- layer 2 ----
    k_gemm2<<<(N + 63) / 64, 256, 0, stream>>>(aggb, b1, w2t, dinv, bufH2, N);
    k_pull64<<<(nwv64 + 3) / 4, 256, 0, stream>>>((const unsigned short*)bufH2, row_ptr, deg, csr4, dinv, b2, out, N);
}